// Round 11
// baseline (3544.019 us; speedup 1.0000x reference)
//
#include <hip/hip_runtime.h>
#include <stdint.h>

// BiLSTM: B=32, T=256, D=1024, H=1024. out (B,T,2H) fp32.
//  k_cvt_x   : x fp32 -> bf16
//  k_pack_wxt: x-part of W{f,i,c,o} -> Wx^T bf16 [4096 gc][1024 k]
//  k_pgemm   : P[t][b][gc] = x@Wx + b (bf16 MFMA 32x32x16), shared by both dirs
//  k_heat    : dense FMA pre-heat (ramps SCLK before the latency-bound kernel)
//  k_lstm    : persistent 256-WG kernel; weights in LDS; h exchanged per step.
// R11 = R9 + PROPER clock test. R10's heater was accidentally blocking (load->
//   waitcnt->burst => 7% duty, matching measured VALUBusy 6.9%). Now: burst of
//   256 FMAs issued BETWEEN the poll load and its first use (waitcnt lands
//   after the burst), all 4 waves poll; plus a dense pre-heat kernel and HEAT
//   bursts during the staging/publish drain windows. Forensics for ~750MHz:
//   MFMA busy-time/step invariant 0.213/0.214us (R1/R9) for a fixed
//   ~155-cycle MFMA workload.

typedef __attribute__((ext_vector_type(8))) short bf16x8;
typedef __attribute__((ext_vector_type(4))) float f32x4;
typedef __attribute__((ext_vector_type(16))) float f32x16;
typedef __attribute__((ext_vector_type(4))) unsigned int u32x4;

// ---- workspace layout (bytes) ----
// [0, 32M)    : h ring [256 slots][2 dir][32 rows][1024 cols] bf16 (k_lstm)
//               xb (16 MB @0) and wxt (8 MB @16M) live here during prep only.
static const size_t XB_OFF  = 0;                 // x bf16: 16 MB (dead in k_lstm)
static const size_t WXT_OFF = 16777216;          // Wx^T bf16: 8 MB (dead in k_lstm)
static const size_t P2_OFF  = 33554432;          // P bf16 [256][32][4096] = 64 MB
static const size_t FLG_OFF = 100663296;         // flags u32 @64B stride: [2 half][128]
static const size_t FLG_SZ  = 16384;

__device__ __forceinline__ unsigned short f2bf(float f) {
    union { float f; unsigned u; } v; v.f = f;
    unsigned r = v.u + 0x7FFFu + ((v.u >> 16) & 1u);
    return (unsigned short)(r >> 16);
}
__device__ __forceinline__ float bf2f(unsigned short h) {
    union { unsigned u; float f; } v; v.u = ((unsigned)h) << 16; return v.f;
}
__device__ __forceinline__ float sigm(float x) {
    return 1.0f / (1.0f + exp2f(x * -1.4426950408889634f));
}
__device__ __forceinline__ float tanh_(float x) {
    return 1.0f - 2.0f / (1.0f + exp2f(x * 2.8853900817779268f));
}
__device__ __forceinline__ void gload16(const void* g, void* l) {
    __builtin_amdgcn_global_load_lds(
        (const __attribute__((address_space(1))) unsigned int*)g,
        (__attribute__((address_space(3))) unsigned int*)l, 16, 0, 0);
}
// 16B store direct to LLC (sc1): publish path for cross-WG h.
__device__ __forceinline__ void gstore16_sc1(void* g, u32x4 v) {
    asm volatile("global_store_dwordx4 %0, %1, off sc1" : : "v"(g), "v"(v) : "memory");
}

// N iterations x 4 pipelined FMA chains (heater; keeps SIMD issue-busy)
#define HEAT(N) do {                                                          \
    _Pragma("unroll")                                                         \
    for (int z_ = 0; z_ < (N); ++z_) {                                        \
        asm volatile("v_fma_f32 %0, %1, %2, %0" : "+v"(hh0) : "v"(hh1), "v"(hh2)); \
        asm volatile("v_fma_f32 %0, %1, %2, %0" : "+v"(hh1) : "v"(hh2), "v"(hh3)); \
        asm volatile("v_fma_f32 %0, %1, %2, %0" : "+v"(hh2) : "v"(hh3), "v"(hh0)); \
        asm volatile("v_fma_f32 %0, %1, %2, %0" : "+v"(hh3) : "v"(hh0), "v"(hh1)); \
    }                                                                         \
} while (0)

// ---------------- clock pre-heat: dense pipelined FMA on all CUs ----------------
__global__ __launch_bounds__(256) void k_heat(int iters) {
    float hh0 = 1.0f + threadIdx.x, hh1 = 1.0001f, hh2 = 0.9999f, hh3 = 1.00001f;
    for (int i = 0; i < iters; ++i) {
        HEAT(16);                                // 64 FMAs/iter
    }
    asm volatile("" :: "v"(hh0), "v"(hh1), "v"(hh2), "v"(hh3));
}

// ---------------- x -> bf16 ----------------
__global__ void k_cvt_x(const float* __restrict__ x, unsigned short* __restrict__ xb, int n) {
    int i = (blockIdx.x * blockDim.x + threadIdx.x) * 4;
    if (i < n) {
        float4 v = *(const float4*)(x + i);
        ushort4 o; o.x = f2bf(v.x); o.y = f2bf(v.y); o.z = f2bf(v.z); o.w = f2bf(v.w);
        *(ushort4*)(xb + i) = o;
    }
}

// ---------------- Wx^T pack ----------------
__global__ __launch_bounds__(256) void k_pack_wxt(
        const float* __restrict__ Wf, const float* __restrict__ Wi,
        const float* __restrict__ Wc, const float* __restrict__ Wo,
        unsigned short* __restrict__ wxt) {
    __shared__ unsigned short tile[64][66];
    const int k0 = blockIdx.x * 64;
    const int gate = blockIdx.y >> 4;
    const int c0 = (blockIdx.y & 15) * 64;
    const float* W = gate == 0 ? Wf : gate == 1 ? Wi : gate == 2 ? Wc : Wo;
    const int t = threadIdx.x;
    #pragma unroll
    for (int i = 0; i < 4; ++i) {
        int id = t + 256 * i;
        int r = id >> 4, fq = id & 15;
        const float* src = W + (size_t)(1024 + k0 + r) * 1024 + c0 + fq * 4;
        float4 v = *(const float4*)src;
        tile[r][fq*4+0] = f2bf(v.x); tile[r][fq*4+1] = f2bf(v.y);
        tile[r][fq*4+2] = f2bf(v.z); tile[r][fq*4+3] = f2bf(v.w);
    }
    __syncthreads();
    #pragma unroll
    for (int i = 0; i < 2; ++i) {
        int id = t + 256 * i;
        int c = id >> 3, kq = id & 7;
        ushort4 a, b;
        a.x = tile[kq*8+0][c]; a.y = tile[kq*8+1][c]; a.z = tile[kq*8+2][c]; a.w = tile[kq*8+3][c];
        b.x = tile[kq*8+4][c]; b.y = tile[kq*8+5][c]; b.z = tile[kq*8+6][c]; b.w = tile[kq*8+7][c];
        unsigned short* o = wxt + (size_t)(gate*1024 + c0 + c) * 1024 + k0 + kq*8;
        *(ushort4*)o = a;
        *((ushort4*)o + 1) = b;
    }
}

// ---------------- P GEMM ----------------
__global__ __launch_bounds__(256) void k_pgemm(
        const unsigned short* __restrict__ xb, const unsigned short* __restrict__ wxt,
        const float* __restrict__ b0, const float* __restrict__ b1,
        const float* __restrict__ b2, const float* __restrict__ b3,
        unsigned short* __restrict__ p2) {
    __shared__ char lds[32768];
    const int n0 = blockIdx.x * 128;
    const int gc0 = blockIdx.y * 128;
    const int tid = threadIdx.x;
    const int lane = tid & 63, w = tid >> 6;
    f32x16 acc[4];
    #pragma unroll
    for (int i = 0; i < 4; ++i)
        #pragma unroll
        for (int j = 0; j < 16; ++j) acc[i][j] = 0.0f;

    for (int kt = 0; kt < 16; ++kt) {
        const int k0 = kt * 64;
        #pragma unroll
        for (int i = 0; i < 4; ++i) {
            int widx = w*4 + i;
            int n = widx*64 + lane;
            int mt = n >> 8, kc = (n >> 5) & 7, r5 = n & 31;
            gload16(xb  + (size_t)(n0  + mt*32 + r5)*1024 + k0 + kc*8, lds + widx*1024);
            gload16(wxt + (size_t)(gc0 + mt*32 + r5)*1024 + k0 + kc*8, lds + 16384 + widx*1024);
        }
        __syncthreads();
        bf16x8 a[4];
        #pragma unroll
        for (int ks = 0; ks < 4; ++ks)
            a[ks] = *(const bf16x8*)(lds + w*4096 + (ks*2 + (lane>>5))*512 + (lane&31)*16);
        #pragma unroll
        for (int nt = 0; nt < 4; ++nt) {
            #pragma unroll
            for (int ks = 0; ks < 4; ++ks) {
                bf16x8 b = *(const bf16x8*)(lds + 16384 + nt*4096 + (ks*2 + (lane>>5))*512 + (lane&31)*16);
                acc[nt] = __builtin_amdgcn_mfma_f32_32x32x16_bf16(a[ks], b, acc[nt], 0, 0, 0);
            }
        }
        __syncthreads();
    }
    const int b_idx = n0 >> 8;
    const int t_base = n0 & 255;
    #pragma unroll
    for (int nt = 0; nt < 4; ++nt) {
        int gc = gc0 + nt*32 + (lane & 31);
        int gate = gc >> 10, col = gc & 1023;
        const float* bp = gate == 0 ? b0 : gate == 1 ? b1 : gate == 2 ? b2 : b3;
        float bias = bp[col];
        #pragma unroll
        for (int r = 0; r < 16; ++r) {
            int row = (r & 3) + 8*(r >> 2) + 4*(lane >> 5);
            int t = t_base + w*32 + row;
            p2[((size_t)t*32 + b_idx)*4096 + gc] = f2bf(acc[nt][r] + bias);
        }
    }
}

// ---------------- persistent BiLSTM recurrence ----------------
#define WPK   0          // 64 KB weight pack (B-frag order, 16x16x32)
#define HFO   65536      // 32 KB h stage, dir F (A-frag order, xor-swizzled)
#define HBO   98304      // 32 KB h stage, dir B
#define REDF  131072     // 4 KB K-split partials F
#define REDB  135168     // 4 KB partials B
#define CSTO  139264     // 1 KB c-state
#define STH_H 140288     // 512 B h bf16 stash [2 dir][16 row][8 col]
#define STH_O 140800     // 1 KB out fp32 stash [2 dir][16 row][8 col]
#define LDS_TOT 141824

extern __shared__ char smem[];

__global__ __launch_bounds__(256, 1) void k_lstm(
    const float* __restrict__ Wf, const float* __restrict__ Wi,
    const float* __restrict__ Wc, const float* __restrict__ Wo,
    const unsigned short* __restrict__ p2,
    unsigned short* __restrict__ hring,  // [256 slot][2 dir][32][1024] bf16
    unsigned* __restrict__ fl,           // flags u32 @ 64B stride: [half][128]
    float* __restrict__ out)             // [32][256][2048] fp32
{
    const int wg = blockIdx.x;
    const int bh = wg & 1;               // batch half (own dependency group)
    const int hc0 = (wg >> 1) * 8;       // owned h-cols
    const int tid = threadIdx.x;
    const int lane = tid & 63, w = tid >> 6;
    __shared__ int s_abort;
    if (tid == 0) s_abort = 0;
    float hh0 = 1.0f + lane, hh1 = 1.0001f, hh2 = 0.9999f, hh3 = 1.00001f;

    // ---- pack recurrent weights (h-part rows 0..1023) into LDS frag order ----
    {
        unsigned short* scr = (unsigned short*)(smem + HFO);
        const float* Wp[4] = {Wf, Wi, Wc, Wo};
        for (int blk = 0; blk < 16; ++blk) {
            int r0 = blk * 64;
            {
                int g = tid >> 6, r = tid & 63;
                const float* src = Wp[g] + (size_t)(r0 + r) * 1024 + hc0;
                float4 v0 = *(const float4*)src;
                float4 v1 = *(const float4*)(src + 4);
                unsigned short* d = scr + r*32 + g*8;
                d[0]=f2bf(v0.x); d[1]=f2bf(v0.y); d[2]=f2bf(v0.z); d[3]=f2bf(v0.w);
                d[4]=f2bf(v1.x); d[5]=f2bf(v1.y); d[6]=f2bf(v1.z); d[7]=f2bf(v1.w);
            }
            __syncthreads();
            {
                int ksl = tid >> 7, nt = (tid >> 6) & 1, l = tid & 63;
                int gcl = nt*16 + (l & 15);
                int gp = gcl >> 3, hc = gcl & 7;
                int ks = (r0 >> 5) + ksl;
                unsigned short tmp[8];
                #pragma unroll
                for (int j = 0; j < 8; ++j) {
                    int kloc = ksl*32 + (l >> 4)*8 + j;
                    tmp[j] = scr[kloc*32 + gp*8 + hc];
                }
                char* dst = smem + WPK + (size_t)((nt*32 + ks)*64 + l)*16;
                ushort4 lo, hi;
                lo.x=tmp[0]; lo.y=tmp[1]; lo.z=tmp[2]; lo.w=tmp[3];
                hi.x=tmp[4]; hi.y=tmp[5]; hi.z=tmp[6]; hi.w=tmp[7];
                *(ushort4*)dst = lo; *((ushort4*)dst + 1) = hi;
            }
            __syncthreads();
        }
    }

    // ---- init c=0 (LDS), h(0)=0 into ring slot 0, publish tag 1 ----
    for (int i = tid; i < 256; i += 256) ((float*)(smem + CSTO))[i] = 0.0f;
    const int d2 = tid >> 7, t2 = tid & 127;
    const int eb = t2 >> 3, ehc = t2 & 7;
    const int ebg = bh*16 + eb, ehcg = hc0 + ehc;
    if ((tid & 1) == 0) {
        unsigned* dst = (unsigned*)(hring + (size_t)d2*32768 + (size_t)ebg*1024 + ehcg);
        __hip_atomic_store(dst, 0u, __ATOMIC_RELAXED, __HIP_MEMORY_SCOPE_AGENT);
    }
    __syncthreads();                              // drains init stores (vmcnt0)
    if (tid == 0)
        __hip_atomic_store(fl + (size_t)bh*2048 + (wg >> 1)*16, 1u,
                           __ATOMIC_RELAXED, __HIP_MEMORY_SCOPE_AGENT);

    for (int s = 0; s < 256; ++s) {
        const int tx = d2 ? (255 - s) : s;
        // P prefetch (cached; no h dependency; hidden under spin+staging)
        const unsigned short* pp = p2 + ((size_t)tx*32 + ebg)*4096 + ehcg;
        unsigned short pf = pp[0], pi = pp[1024], pc = pp[2048], po = pp[3072];

        // ---- wait: ALL 4 waves poll (w0,2: flags 0-63; w1,3: 64-127).
        //      NON-BLOCKING heater: 256 FMAs issued between the poll load and
        //      its first use -> waitcnt lands after the burst (50-100% duty).
        {
            const unsigned* pw = fl + (size_t)bh*2048 + ((w & 1)*64 + lane)*16;
            const unsigned tag = (unsigned)(s + 1);
            long guard = 0;
            for (;;) {
                unsigned v = __hip_atomic_load(pw, __ATOMIC_RELAXED, __HIP_MEMORY_SCOPE_AGENT);
                HEAT(64);                         // 256 FMAs while load in flight
                if (__all(v >= tag)) break;
                if (++guard >= (1L << 21)) { if (lane == 0) s_abort = 1; break; }
            }
        }
        __syncthreads();
        if (s_abort) break;

        // ---- stage h (both dirs) from ring slot s: PLAIN CACHED gload16 ----
        {
            const unsigned short* hsF = hring + (size_t)s*65536;
            const unsigned short* hsB = hsF + 32768;
            #pragma unroll
            for (int j = 0; j < 8; ++j) {
                int c = w*8 + j;                  // chunks 0..31
                int kc = c*4 + (lane >> 4);
                int r16 = (lane & 15) ^ (kc & 7);
                size_t off = (size_t)(bh*16 + r16)*1024 + kc*8;
                gload16(hsF + off, smem + HFO + c*1024);
                gload16(hsB + off, smem + HBO + c*1024);
            }
        }
        HEAT(32);                                 // heat during the stage drain
        __syncthreads();                          // drains vmcnt (staging + P)

        // ---- MFMA: gates = h @ Wh (M=16, N=32, K=1024), K split across wave pairs ----
        {
            const int nt = w & 1, kh = w >> 1;
            f32x4 aF = {0.f,0.f,0.f,0.f}, aB = {0.f,0.f,0.f,0.f};
            #pragma unroll 4
            for (int k8 = 0; k8 < 16; ++k8) {
                int ks = kh*16 + k8;
                int kc = ks*4 + (lane >> 4);
                int ao = kc*256 + (((lane & 15)*16) ^ ((kc & 7) << 4));
                bf16x8 bfr = *(const bf16x8*)(smem + WPK + (size_t)((nt*32 + ks)*64 + lane)*16);
                bf16x8 afF = *(const bf16x8*)(smem + HFO + ao);
                aF = __builtin_amdgcn_mfma_f32_16x16x32_bf16(afF, bfr, aF, 0, 0, 0);
                bf16x8 afB = *(const bf16x8*)(smem + HBO + ao);
                aB = __builtin_amdgcn_mfma_f32_16x16x32_bf16(afB, bfr, aB, 0, 0, 0);
            }
            float* rf = (float*)(smem + REDF) + w*256;
            float* rb = (float*)(smem + REDB) + w*256;
            #pragma unroll
            for (int r = 0; r < 4; ++r) {
                int row = (lane >> 4)*4 + r;
                rf[row*16 + (lane & 15)] = aF[r];
                rb[row*16 + (lane & 15)] = aB[r];
            }
        }
        __syncthreads();

        // ---- elementwise: t<128 does F, t>=128 does B; stash h+out in LDS ----
        {
            const char* red = smem + (d2 ? REDB : REDF);
            float* cst = (float*)(smem + CSTO) + (size_t)(d2*16 + eb)*8 + ehc;
            unsigned short pv[4] = {pf, pi, pc, po};
            float pre[4];
            #pragma unroll
            for (int g = 0; g < 4; ++g) {
                int gc = g*8 + ehc;
                int nt = gc >> 4, col = gc & 15;
                float s0 = ((const float*)red)[nt*256 + eb*16 + col];
                float s1 = ((const float*)red)[(2 + nt)*256 + eb*16 + col];
                pre[g] = s0 + s1 + bf2f(pv[g]);
            }
            float fg = sigm(pre[0]), ig = sigm(pre[1]), gg = tanh_(pre[2]), og = sigm(pre[3]);
            float cn = fg * (*cst) + ig * gg;
            *cst = cn;
            float hv = og * tanh_(cn);
            ((unsigned short*)(smem + STH_H))[d2*128 + t2] = f2bf(hv);
            ((float*)(smem + STH_O))[d2*128 + t2] = hv;
        }
        __syncthreads();

        // ---- h publish into virgin ring slot s+1: 32 x 16B sc1 stores ----
        if (s < 255) {
            if (tid < 32) {
                int d2s = tid >> 4, ebs = tid & 15;
                u32x4 v = *(const u32x4*)(smem + STH_H + (d2s*16 + ebs)*16);
                gstore16_sc1(hring + (size_t)(s + 1)*65536 + (size_t)d2s*32768
                                   + (size_t)(bh*16 + ebs)*1024 + hc0, v);
            }
            HEAT(32);                             // heat during the publish drain
            __syncthreads();                      // drains h stores (vmcnt0)
            if (tid == 0)
                __hip_atomic_store(fl + (size_t)bh*2048 + (wg >> 1)*16, (unsigned)(s + 2),
                                   __ATOMIC_RELAXED, __HIP_MEMORY_SCOPE_AGENT);
        }

        // ---- out stores (post-publish, off critical path): 16B chunks ----
        if (tid >= 64 && tid < 128) {
            int i = tid - 64;
            int chunk = i >> 1, half = i & 1;       // chunk = d2s*16 + ebs
            int d2s = chunk >> 4, ebs = chunk & 15;
            int txs = d2s ? (255 - s) : s;
            float4 v = *(const float4*)(smem + STH_O + chunk*32 + half*16);
            *(float4*)(out + ((size_t)(bh*16 + ebs)*256 + txs)*2048
                           + (size_t)d2s*1024 + hc0 + half*4) = v;
        }
    }
    asm volatile("" :: "v"(hh0), "v"(hh1), "v"(hh2), "v"(hh3));  // keep heater live
}

extern "C" void kernel_launch(void* const* d_in, const int* in_sizes, int n_in,
                              void* d_out, int out_size, void* d_ws, size_t ws_size,
                              hipStream_t stream) {
    const float* x  = (const float*)d_in[0];
    const float* Wf = (const float*)d_in[1]; const float* bf_ = (const float*)d_in[2];
    const float* Wi = (const float*)d_in[3]; const float* bi_ = (const float*)d_in[4];
    const float* Wc = (const float*)d_in[5]; const float* bc_ = (const float*)d_in[6];
    const float* Wo = (const float*)d_in[7]; const float* bo_ = (const float*)d_in[8];
    char* ws = (char*)d_ws;
    unsigned short* xb    = (unsigned short*)(ws + XB_OFF);
    unsigned short* wxt   = (unsigned short*)(ws + WXT_OFF);
    unsigned short* p2    = (unsigned short*)(ws + P2_OFF);
    unsigned short* hring = (unsigned short*)(ws + XB_OFF);   // overlays dead xb/wxt
    unsigned*       fl    = (unsigned*)(ws + FLG_OFF);

    hipMemsetAsync(ws + FLG_OFF, 0, FLG_SZ, stream);
    k_cvt_x<<<8192, 256, 0, stream>>>(x, xb, 32*256*1024);
    k_pack_wxt<<<dim3(16, 64), 256, 0, stream>>>(Wf, Wi, Wc, Wo, wxt);
    k_pgemm<<<dim3(64, 32), 256, 0, stream>>>(xb, wxt, bf_, bi_, bc_, bo_, p2);
    k_heat<<<2048, 256, 0, stream>>>(1200);      // ~50-160us dense FMA: ramp SCLK
    hipFuncSetAttribute((const void*)k_lstm, hipFuncAttributeMaxDynamicSharedMemorySize, LDS_TOT);
    k_lstm<<<256, 256, LDS_TOT, stream>>>(Wf, Wi, Wc, Wo, p2, hring, fl, (float*)d_out);
}

// Round 12
// 3128.587 us; speedup vs baseline: 1.1328x; 1.1328x over previous
//
#include <hip/hip_runtime.h>
#include <stdint.h>

// BiLSTM: B=32, T=256, D=1024, H=1024. out (B,T,2H) fp32.
//  k_cvt_x   : x fp32 -> bf16
//  k_pack_wxt: x-part of W{f,i,c,o} -> Wx^T bf16 [4096 gc][1024 k]
//  k_pgemm   : P[t][b][gc] = x@Wx + b (bf16 MFMA 32x32x16), shared by both dirs
//  k_lstm    : persistent 256-WG kernel; weights in LDS; h exchanged per step.
// R12 = R9 base (heater removed; R11 showed clock theory was a bad cycle-count)
//   + STAGGERED DIRECTIONS: F and B are independent chains, so run them as two
//   sequential phases per step with per-dir flags. Each dir's sync round-trip
//   (publish->drain->flag->remote detect) hides under the OTHER dir's
//   stage+MFMA+elem phase. Publish directly from elementwise registers
//   (pair-shfl 4B agent stores) - drops the stash barrier per dir.

typedef __attribute__((ext_vector_type(8))) short bf16x8;
typedef __attribute__((ext_vector_type(4))) float f32x4;
typedef __attribute__((ext_vector_type(16))) float f32x16;

// ---- workspace layout (bytes) ----
// [0, 32M): h ring [256 slot][2 dir][32 rows][1024 cols] bf16 (k_lstm);
//           xb (16MB @0) / wxt (8MB @16M) live here during prep only.
static const size_t XB_OFF  = 0;
static const size_t WXT_OFF = 16777216;
static const size_t P2_OFF  = 33554432;          // P bf16 [256][32][4096] = 64 MB
static const size_t FLG_OFF = 100663296;         // u32 @64B: F[2 half][128], B at +16KB
static const size_t FLG_SZ  = 32768;

__device__ __forceinline__ unsigned short f2bf(float f) {
    union { float f; unsigned u; } v; v.f = f;
    unsigned r = v.u + 0x7FFFu + ((v.u >> 16) & 1u);
    return (unsigned short)(r >> 16);
}
__device__ __forceinline__ float bf2f(unsigned short h) {
    union { unsigned u; float f; } v; v.u = ((unsigned)h) << 16; return v.f;
}
__device__ __forceinline__ float sigm(float x) {
    return 1.0f / (1.0f + exp2f(x * -1.4426950408889634f));
}
__device__ __forceinline__ float tanh_(float x) {
    return 1.0f - 2.0f / (1.0f + exp2f(x * 2.8853900817779268f));
}
__device__ __forceinline__ void gload16(const void* g, void* l) {
    __builtin_amdgcn_global_load_lds(
        (const __attribute__((address_space(1))) unsigned int*)g,
        (__attribute__((address_space(3))) unsigned int*)l, 16, 0, 0);
}

// ---------------- x -> bf16 ----------------
__global__ void k_cvt_x(const float* __restrict__ x, unsigned short* __restrict__ xb, int n) {
    int i = (blockIdx.x * blockDim.x + threadIdx.x) * 4;
    if (i < n) {
        float4 v = *(const float4*)(x + i);
        ushort4 o; o.x = f2bf(v.x); o.y = f2bf(v.y); o.z = f2bf(v.z); o.w = f2bf(v.w);
        *(ushort4*)(xb + i) = o;
    }
}

// ---------------- Wx^T pack ----------------
__global__ __launch_bounds__(256) void k_pack_wxt(
        const float* __restrict__ Wf, const float* __restrict__ Wi,
        const float* __restrict__ Wc, const float* __restrict__ Wo,
        unsigned short* __restrict__ wxt) {
    __shared__ unsigned short tile[64][66];
    const int k0 = blockIdx.x * 64;
    const int gate = blockIdx.y >> 4;
    const int c0 = (blockIdx.y & 15) * 64;
    const float* W = gate == 0 ? Wf : gate == 1 ? Wi : gate == 2 ? Wc : Wo;
    const int t = threadIdx.x;
    #pragma unroll
    for (int i = 0; i < 4; ++i) {
        int id = t + 256 * i;
        int r = id >> 4, fq = id & 15;
        const float* src = W + (size_t)(1024 + k0 + r) * 1024 + c0 + fq * 4;
        float4 v = *(const float4*)src;
        tile[r][fq*4+0] = f2bf(v.x); tile[r][fq*4+1] = f2bf(v.y);
        tile[r][fq*4+2] = f2bf(v.z); tile[r][fq*4+3] = f2bf(v.w);
    }
    __syncthreads();
    #pragma unroll
    for (int i = 0; i < 2; ++i) {
        int id = t + 256 * i;
        int c = id >> 3, kq = id & 7;
        ushort4 a, b;
        a.x = tile[kq*8+0][c]; a.y = tile[kq*8+1][c]; a.z = tile[kq*8+2][c]; a.w = tile[kq*8+3][c];
        b.x = tile[kq*8+4][c]; b.y = tile[kq*8+5][c]; b.z = tile[kq*8+6][c]; b.w = tile[kq*8+7][c];
        unsigned short* o = wxt + (size_t)(gate*1024 + c0 + c) * 1024 + k0 + kq*8;
        *(ushort4*)o = a;
        *((ushort4*)o + 1) = b;
    }
}

// ---------------- P GEMM ----------------
__global__ __launch_bounds__(256) void k_pgemm(
        const unsigned short* __restrict__ xb, const unsigned short* __restrict__ wxt,
        const float* __restrict__ b0, const float* __restrict__ b1,
        const float* __restrict__ b2, const float* __restrict__ b3,
        unsigned short* __restrict__ p2) {
    __shared__ char lds[32768];
    const int n0 = blockIdx.x * 128;
    const int gc0 = blockIdx.y * 128;
    const int tid = threadIdx.x;
    const int lane = tid & 63, w = tid >> 6;
    f32x16 acc[4];
    #pragma unroll
    for (int i = 0; i < 4; ++i)
        #pragma unroll
        for (int j = 0; j < 16; ++j) acc[i][j] = 0.0f;

    for (int kt = 0; kt < 16; ++kt) {
        const int k0 = kt * 64;
        #pragma unroll
        for (int i = 0; i < 4; ++i) {
            int widx = w*4 + i;
            int n = widx*64 + lane;
            int mt = n >> 8, kc = (n >> 5) & 7, r5 = n & 31;
            gload16(xb  + (size_t)(n0  + mt*32 + r5)*1024 + k0 + kc*8, lds + widx*1024);
            gload16(wxt + (size_t)(gc0 + mt*32 + r5)*1024 + k0 + kc*8, lds + 16384 + widx*1024);
        }
        __syncthreads();
        bf16x8 a[4];
        #pragma unroll
        for (int ks = 0; ks < 4; ++ks)
            a[ks] = *(const bf16x8*)(lds + w*4096 + (ks*2 + (lane>>5))*512 + (lane&31)*16);
        #pragma unroll
        for (int nt = 0; nt < 4; ++nt) {
            #pragma unroll
            for (int ks = 0; ks < 4; ++ks) {
                bf16x8 b = *(const bf16x8*)(lds + 16384 + nt*4096 + (ks*2 + (lane>>5))*512 + (lane&31)*16);
                acc[nt] = __builtin_amdgcn_mfma_f32_32x32x16_bf16(a[ks], b, acc[nt], 0, 0, 0);
            }
        }
        __syncthreads();
    }
    const int b_idx = n0 >> 8;
    const int t_base = n0 & 255;
    #pragma unroll
    for (int nt = 0; nt < 4; ++nt) {
        int gc = gc0 + nt*32 + (lane & 31);
        int gate = gc >> 10, col = gc & 1023;
        const float* bp = gate == 0 ? b0 : gate == 1 ? b1 : gate == 2 ? b2 : b3;
        float bias = bp[col];
        #pragma unroll
        for (int r = 0; r < 16; ++r) {
            int row = (r & 3) + 8*(r >> 2) + 4*(lane >> 5);
            int t = t_base + w*32 + row;
            p2[((size_t)t*32 + b_idx)*4096 + gc] = f2bf(acc[nt][r] + bias);
        }
    }
}

// ---------------- persistent BiLSTM recurrence ----------------
#define WPK   0          // 64 KB weight pack (B-frag order, 16x16x32)
#define HFO   65536      // 32 KB h stage, dir F (A-frag order, xor-swizzled)
#define HBO   98304      // 32 KB h stage, dir B
#define RED   131072     // 4 KB K-split partials (reused F then B)
#define CSTO  135168     // 1 KB c-state
#define STH_O 136192     // 1 KB out fp32 stash [2 dir][16 row][8 col]
#define LDS_TOT 137216

extern __shared__ char smem[];

__global__ __launch_bounds__(256, 1) void k_lstm(
    const float* __restrict__ Wf, const float* __restrict__ Wi,
    const float* __restrict__ Wc, const float* __restrict__ Wo,
    const unsigned short* __restrict__ p2,
    unsigned short* __restrict__ hring,  // [256 slot][2 dir][32][1024] bf16
    unsigned* __restrict__ fl,           // F flags: [half][128] u32@64B; B at +4096 u32
    float* __restrict__ out)             // [32][256][2048] fp32
{
    const int wg = blockIdx.x;
    const int bh = wg & 1;               // batch half (own dependency group)
    const int hc0 = (wg >> 1) * 8;       // owned h-cols
    const int tid = threadIdx.x;
    const int lane = tid & 63, w = tid >> 6;
    unsigned* flF = fl;
    unsigned* flB = fl + 4096;
    __shared__ int s_abort;
    if (tid == 0) s_abort = 0;

    // ---- pack recurrent weights (h-part rows 0..1023) into LDS frag order ----
    {
        unsigned short* scr = (unsigned short*)(smem + HFO);
        const float* Wp[4] = {Wf, Wi, Wc, Wo};
        for (int blk = 0; blk < 16; ++blk) {
            int r0 = blk * 64;
            {
                int g = tid >> 6, r = tid & 63;
                const float* src = Wp[g] + (size_t)(r0 + r) * 1024 + hc0;
                float4 v0 = *(const float4*)src;
                float4 v1 = *(const float4*)(src + 4);
                unsigned short* d = scr + r*32 + g*8;
                d[0]=f2bf(v0.x); d[1]=f2bf(v0.y); d[2]=f2bf(v0.z); d[3]=f2bf(v0.w);
                d[4]=f2bf(v1.x); d[5]=f2bf(v1.y); d[6]=f2bf(v1.z); d[7]=f2bf(v1.w);
            }
            __syncthreads();
            {
                int ksl = tid >> 7, nt = (tid >> 6) & 1, l = tid & 63;
                int gcl = nt*16 + (l & 15);
                int gp = gcl >> 3, hc = gcl & 7;
                int ks = (r0 >> 5) + ksl;
                unsigned short tmp[8];
                #pragma unroll
                for (int j = 0; j < 8; ++j) {
                    int kloc = ksl*32 + (l >> 4)*8 + j;
                    tmp[j] = scr[kloc*32 + gp*8 + hc];
                }
                char* dst = smem + WPK + (size_t)((nt*32 + ks)*64 + l)*16;
                ushort4 lo, hi;
                lo.x=tmp[0]; lo.y=tmp[1]; lo.z=tmp[2]; lo.w=tmp[3];
                hi.x=tmp[4]; hi.y=tmp[5]; hi.z=tmp[6]; hi.w=tmp[7];
                *(ushort4*)dst = lo; *((ushort4*)dst + 1) = hi;
            }
            __syncthreads();
        }
    }

    // ---- init c=0 (LDS), h(0)=0 into ring slot 0, publish tags 1 ----
    for (int i = tid; i < 256; i += 256) ((float*)(smem + CSTO))[i] = 0.0f;
    const int d2 = tid >> 7, t2 = tid & 127;
    const int eb = t2 >> 3, ehc = t2 & 7;
    const int ebg = bh*16 + eb, ehcg = hc0 + ehc;
    if ((tid & 1) == 0) {
        unsigned* dst = (unsigned*)(hring + (size_t)d2*32768 + (size_t)ebg*1024 + ehcg);
        __hip_atomic_store(dst, 0u, __ATOMIC_RELAXED, __HIP_MEMORY_SCOPE_AGENT);
    }
    __syncthreads();                              // drains init stores (vmcnt0)
    if (tid == 0) {
        __hip_atomic_store(flF + (size_t)bh*2048 + (wg >> 1)*16, 1u,
                           __ATOMIC_RELAXED, __HIP_MEMORY_SCOPE_AGENT);
        __hip_atomic_store(flB + (size_t)bh*2048 + (wg >> 1)*16, 1u,
                           __ATOMIC_RELAXED, __HIP_MEMORY_SCOPE_AGENT);
    }

    for (int s = 0; s < 256; ++s) {
        const int tx = d2 ? (255 - s) : s;
        const unsigned tag = (unsigned)(s + 1);
        // P prefetch for own dir (cached; drain folds into stage barrier)
        const unsigned short* pp = p2 + ((size_t)tx*32 + ebg)*4096 + ehcg;
        unsigned short pf = pp[0], pi = pp[1024], pc = pp[2048], po = pp[3072];

        // ============ F phase ============
        if (w < 2) {                              // wait F(s): published 1 phase ago
            const unsigned* pw = flF + (size_t)bh*2048 + (w*64 + lane)*16;
            long guard = 0;
            for (;;) {
                unsigned v = __hip_atomic_load(pw, __ATOMIC_RELAXED, __HIP_MEMORY_SCOPE_AGENT);
                if (__all(v >= tag)) break;
                if (++guard >= (1L << 21)) { if (lane == 0) s_abort = 1; break; }
            }
        }
        __syncthreads();
        if (s_abort) break;

        {   // stage F from ring slot s (cached loads; virgin slot)
            const unsigned short* hsF = hring + (size_t)s*65536;
            #pragma unroll
            for (int j = 0; j < 8; ++j) {
                int c = w*8 + j;
                int kc = c*4 + (lane >> 4);
                int r16 = (lane & 15) ^ (kc & 7);
                gload16(hsF + (size_t)(bh*16 + r16)*1024 + kc*8, smem + HFO + c*1024);
            }
        }
        __syncthreads();                          // drains F stage (+P loads)

        {   // MFMA F: K split across wave pairs, partials -> RED
            const int nt = w & 1, kh = w >> 1;
            f32x4 aF = {0.f,0.f,0.f,0.f};
            #pragma unroll 4
            for (int k8 = 0; k8 < 16; ++k8) {
                int ks = kh*16 + k8;
                int kc = ks*4 + (lane >> 4);
                int ao = kc*256 + (((lane & 15)*16) ^ ((kc & 7) << 4));
                bf16x8 bfr = *(const bf16x8*)(smem + WPK + (size_t)((nt*32 + ks)*64 + lane)*16);
                bf16x8 afF = *(const bf16x8*)(smem + HFO + ao);
                aF = __builtin_amdgcn_mfma_f32_16x16x32_bf16(afF, bfr, aF, 0, 0, 0);
            }
            float* rf = (float*)(smem + RED) + w*256;
            #pragma unroll
            for (int r = 0; r < 4; ++r) {
                int row = (lane >> 4)*4 + r;
                rf[row*16 + (lane & 15)] = aF[r];
            }
        }
        __syncthreads();

        if (tid < 128) {                          // elem F + direct publish
            const float* red = (const float*)(smem + RED);
            float* cst = (float*)(smem + CSTO) + (size_t)eb*8 + ehc;
            unsigned short pv[4] = {pf, pi, pc, po};
            float pre[4];
            #pragma unroll
            for (int g = 0; g < 4; ++g) {
                int gc = g*8 + ehc;
                int nt = gc >> 4, col = gc & 15;
                pre[g] = red[nt*256 + eb*16 + col] + red[(2 + nt)*256 + eb*16 + col]
                       + bf2f(pv[g]);
            }
            float fg = sigm(pre[0]), ig = sigm(pre[1]), gg = tanh_(pre[2]), og = sigm(pre[3]);
            float cn = fg * (*cst) + ig * gg;
            *cst = cn;
            float hv = og * tanh_(cn);
            ((float*)(smem + STH_O))[t2] = hv;
            unsigned short hb16 = f2bf(hv);
            int oth = __shfl_xor((int)(unsigned)hb16, 1, 64);
            if ((tid & 1) == 0 && s < 255) {
                unsigned pk = (unsigned)hb16 | ((unsigned)oth << 16);
                unsigned* dst = (unsigned*)(hring + (size_t)(s + 1)*65536
                                            + (size_t)ebg*1024 + ehcg);
                __hip_atomic_store(dst, pk, __ATOMIC_RELAXED, __HIP_MEMORY_SCOPE_AGENT);
            }
        }
        __syncthreads();                          // drains F publish (vmcnt0)
        if (tid == 0 && s < 255)
            __hip_atomic_store(flF + (size_t)bh*2048 + (wg >> 1)*16, tag + 1,
                               __ATOMIC_RELAXED, __HIP_MEMORY_SCOPE_AGENT);

        // ============ B phase (F(s+1) RT hides under this) ============
        if (w < 2) {                              // wait B(s)
            const unsigned* pw = flB + (size_t)bh*2048 + (w*64 + lane)*16;
            long guard = 0;
            for (;;) {
                unsigned v = __hip_atomic_load(pw, __ATOMIC_RELAXED, __HIP_MEMORY_SCOPE_AGENT);
                if (__all(v >= tag)) break;
                if (++guard >= (1L << 21)) { if (lane == 0) s_abort = 1; break; }
            }
        }
        __syncthreads();
        if (s_abort) break;

        {   // stage B
            const unsigned short* hsB = hring + (size_t)s*65536 + 32768;
            #pragma unroll
            for (int j = 0; j < 8; ++j) {
                int c = w*8 + j;
                int kc = c*4 + (lane >> 4);
                int r16 = (lane & 15) ^ (kc & 7);
                gload16(hsB + (size_t)(bh*16 + r16)*1024 + kc*8, smem + HBO + c*1024);
            }
        }
        __syncthreads();                          // drains B stage

        {   // MFMA B -> RED (reused; F consumed it before this barrier chain)
            const int nt = w & 1, kh = w >> 1;
            f32x4 aB = {0.f,0.f,0.f,0.f};
            #pragma unroll 4
            for (int k8 = 0; k8 < 16; ++k8) {
                int ks = kh*16 + k8;
                int kc = ks*4 + (lane >> 4);
                int ao = kc*256 + (((lane & 15)*16) ^ ((kc & 7) << 4));
                bf16x8 bfr = *(const bf16x8*)(smem + WPK + (size_t)((nt*32 + ks)*64 + lane)*16);
                bf16x8 afB = *(const bf16x8*)(smem + HBO + ao);
                aB = __builtin_amdgcn_mfma_f32_16x16x32_bf16(afB, bfr, aB, 0, 0, 0);
            }
            float* rb = (float*)(smem + RED) + w*256;
            #pragma unroll
            for (int r = 0; r < 4; ++r) {
                int row = (lane >> 4)*4 + r;
                rb[row*16 + (lane & 15)] = aB[r];
            }
        }
        __syncthreads();

        if (tid >= 128) {                         // elem B + direct publish
            const float* red = (const float*)(smem + RED);
            float* cst = (float*)(smem + CSTO) + (size_t)(16 + eb)*8 + ehc;
            unsigned short pv[4] = {pf, pi, pc, po};
            float pre[4];
            #pragma unroll
            for (int g = 0; g < 4; ++g) {
                int gc = g*8 + ehc;
                int nt = gc >> 4, col = gc & 15;
                pre[g] = red[nt*256 + eb*16 + col] + red[(2 + nt)*256 + eb*16 + col]
                       + bf2f(pv[g]);
            }
            float fg = sigm(pre[0]), ig = sigm(pre[1]), gg = tanh_(pre[2]), og = sigm(pre[3]);
            float cn = fg * (*cst) + ig * gg;
            *cst = cn;
            float hv = og * tanh_(cn);
            ((float*)(smem + STH_O))[128 + t2] = hv;
            unsigned short hb16 = f2bf(hv);
            int oth = __shfl_xor((int)(unsigned)hb16, 1, 64);
            if ((tid & 1) == 0 && s < 255) {
                unsigned pk = (unsigned)hb16 | ((unsigned)oth << 16);
                unsigned* dst = (unsigned*)(hring + (size_t)(s + 1)*65536 + 32768
                                            + (size_t)ebg*1024 + ehcg);
                __hip_atomic_store(dst, pk, __ATOMIC_RELAXED, __HIP_MEMORY_SCOPE_AGENT);
            }
        }
        __syncthreads();                          // drains B publish (vmcnt0)
        if (tid == 0 && s < 255)
            __hip_atomic_store(flB + (size_t)bh*2048 + (wg >> 1)*16, tag + 1,
                               __ATOMIC_RELAXED, __HIP_MEMORY_SCOPE_AGENT);

        // ---- out stores (post-publish; drain hides under next waitF) ----
        if (tid >= 64 && tid < 128) {
            int i = tid - 64;
            int chunk = i >> 1, half = i & 1;       // chunk = d2s*16 + ebs
            int d2s = chunk >> 4, ebs = chunk & 15;
            int txs = d2s ? (255 - s) : s;
            float4 v = *(const float4*)(smem + STH_O + chunk*32 + half*16);
            *(float4*)(out + ((size_t)(bh*16 + ebs)*256 + txs)*2048
                           + (size_t)d2s*1024 + hc0 + half*4) = v;
        }
    }
}

extern "C" void kernel_launch(void* const* d_in, const int* in_sizes, int n_in,
                              void* d_out, int out_size, void* d_ws, size_t ws_size,
                              hipStream_t stream) {
    const float* x  = (const float*)d_in[0];
    const float* Wf = (const float*)d_in[1]; const float* bf_ = (const float*)d_in[2];
    const float* Wi = (const float*)d_in[3]; const float* bi_ = (const float*)d_in[4];
    const float* Wc = (const float*)d_in[5]; const float* bc_ = (const float*)d_in[6];
    const float* Wo = (const float*)d_in[7]; const float* bo_ = (const float*)d_in[8];
    char* ws = (char*)d_ws;
    unsigned short* xb    = (unsigned short*)(ws + XB_OFF);
    unsigned short* wxt   = (unsigned short*)(ws + WXT_OFF);
    unsigned short* p2    = (unsigned short*)(ws + P2_OFF);
    unsigned short* hring = (unsigned short*)(ws + XB_OFF);   // overlays dead xb/wxt
    unsigned*       fl    = (unsigned*)(ws + FLG_OFF);

    hipMemsetAsync(ws + FLG_OFF, 0, FLG_SZ, stream);
    k_cvt_x<<<8192, 256, 0, stream>>>(x, xb, 32*256*1024);
    k_pack_wxt<<<dim3(16, 64), 256, 0, stream>>>(Wf, Wi, Wc, Wo, wxt);
    k_pgemm<<<dim3(64, 32), 256, 0, stream>>>(xb, wxt, bf_, bi_, bc_, bo_, p2);
    hipFuncSetAttribute((const void*)k_lstm, hipFuncAttributeMaxDynamicSharedMemorySize, LDS_TOT);
    k_lstm<<<256, 256, LDS_TOT, stream>>>(Wf, Wi, Wc, Wo, p2, hring, fl, (float*)d_out);
}

// Round 13
// 1489.288 us; speedup vs baseline: 2.3797x; 2.1007x over previous
//
#include <hip/hip_runtime.h>
#include <stdint.h>

// BiLSTM: B=32, T=256, D=1024, H=1024. out (B,T,2H) fp32.
//  k_cvt_x   : x fp32 -> bf16
//  k_pack_wxt: x-part of W{f,i,c,o} -> Wx^T bf16 [4096 gc][1024 k]
//  k_pgemm   : P[t][b][gc] = x@Wx + b (bf16 MFMA 32x32x16), shared by both dirs
//  k_lstm    : persistent 256-WG kernel; weights in LDS; h exchanged per step.
// R13 = R9 base (best: 2280us) + DIRECT-TO-VGPR h staging. Each wave's MFMA
//   A-fragments are wave-private, so the global->LDS->reg bounce (gload_lds +
//   drain barrier + ds_read) is pure overhead. Now: 32x16B cached loads per
//   wave straight into statically-indexed frag registers, consumed by the
//   MFMA loop (compiler pipelines loads vs per-use vmcnt). Removes 2 barriers
//   + the LDS hop from the step critical path. LDS 137KB->75KB, VGPR ~180
//   (occupancy already 1 WG/CU at 256 WGs - free).

typedef __attribute__((ext_vector_type(8))) short bf16x8;
typedef __attribute__((ext_vector_type(4))) float f32x4;
typedef __attribute__((ext_vector_type(16))) float f32x16;
typedef __attribute__((ext_vector_type(4))) unsigned int u32x4;

// ---- workspace layout (bytes) ----
// [0, 32M): h ring [256 slot][2 dir][32 rows][1024 cols] bf16 (k_lstm);
//           xb (16MB @0) / wxt (8MB @16M) live here during prep only.
static const size_t XB_OFF  = 0;
static const size_t WXT_OFF = 16777216;
static const size_t P2_OFF  = 33554432;          // P bf16 [256][32][4096] = 64 MB
static const size_t FLG_OFF = 100663296;         // flags u32 @64B: [2 half][128]
static const size_t FLG_SZ  = 16384;

__device__ __forceinline__ unsigned short f2bf(float f) {
    union { float f; unsigned u; } v; v.f = f;
    unsigned r = v.u + 0x7FFFu + ((v.u >> 16) & 1u);
    return (unsigned short)(r >> 16);
}
__device__ __forceinline__ float bf2f(unsigned short h) {
    union { unsigned u; float f; } v; v.u = ((unsigned)h) << 16; return v.f;
}
__device__ __forceinline__ float sigm(float x) {
    return 1.0f / (1.0f + exp2f(x * -1.4426950408889634f));
}
__device__ __forceinline__ float tanh_(float x) {
    return 1.0f - 2.0f / (1.0f + exp2f(x * 2.8853900817779268f));
}
__device__ __forceinline__ void gload16(const void* g, void* l) {
    __builtin_amdgcn_global_load_lds(
        (const __attribute__((address_space(1))) unsigned int*)g,
        (__attribute__((address_space(3))) unsigned int*)l, 16, 0, 0);
}
// 16B store direct to LLC (sc1): publish path for cross-WG h.
__device__ __forceinline__ void gstore16_sc1(void* g, u32x4 v) {
    asm volatile("global_store_dwordx4 %0, %1, off sc1" : : "v"(g), "v"(v) : "memory");
}

// ---------------- x -> bf16 ----------------
__global__ void k_cvt_x(const float* __restrict__ x, unsigned short* __restrict__ xb, int n) {
    int i = (blockIdx.x * blockDim.x + threadIdx.x) * 4;
    if (i < n) {
        float4 v = *(const float4*)(x + i);
        ushort4 o; o.x = f2bf(v.x); o.y = f2bf(v.y); o.z = f2bf(v.z); o.w = f2bf(v.w);
        *(ushort4*)(xb + i) = o;
    }
}

// ---------------- Wx^T pack ----------------
__global__ __launch_bounds__(256) void k_pack_wxt(
        const float* __restrict__ Wf, const float* __restrict__ Wi,
        const float* __restrict__ Wc, const float* __restrict__ Wo,
        unsigned short* __restrict__ wxt) {
    __shared__ unsigned short tile[64][66];
    const int k0 = blockIdx.x * 64;
    const int gate = blockIdx.y >> 4;
    const int c0 = (blockIdx.y & 15) * 64;
    const float* W = gate == 0 ? Wf : gate == 1 ? Wi : gate == 2 ? Wc : Wo;
    const int t = threadIdx.x;
    #pragma unroll
    for (int i = 0; i < 4; ++i) {
        int id = t + 256 * i;
        int r = id >> 4, fq = id & 15;
        const float* src = W + (size_t)(1024 + k0 + r) * 1024 + c0 + fq * 4;
        float4 v = *(const float4*)src;
        tile[r][fq*4+0] = f2bf(v.x); tile[r][fq*4+1] = f2bf(v.y);
        tile[r][fq*4+2] = f2bf(v.z); tile[r][fq*4+3] = f2bf(v.w);
    }
    __syncthreads();
    #pragma unroll
    for (int i = 0; i < 2; ++i) {
        int id = t + 256 * i;
        int c = id >> 3, kq = id & 7;
        ushort4 a, b;
        a.x = tile[kq*8+0][c]; a.y = tile[kq*8+1][c]; a.z = tile[kq*8+2][c]; a.w = tile[kq*8+3][c];
        b.x = tile[kq*8+4][c]; b.y = tile[kq*8+5][c]; b.z = tile[kq*8+6][c]; b.w = tile[kq*8+7][c];
        unsigned short* o = wxt + (size_t)(gate*1024 + c0 + c) * 1024 + k0 + kq*8;
        *(ushort4*)o = a;
        *((ushort4*)o + 1) = b;
    }
}

// ---------------- P GEMM ----------------
__global__ __launch_bounds__(256) void k_pgemm(
        const unsigned short* __restrict__ xb, const unsigned short* __restrict__ wxt,
        const float* __restrict__ b0, const float* __restrict__ b1,
        const float* __restrict__ b2, const float* __restrict__ b3,
        unsigned short* __restrict__ p2) {
    __shared__ char lds[32768];
    const int n0 = blockIdx.x * 128;
    const int gc0 = blockIdx.y * 128;
    const int tid = threadIdx.x;
    const int lane = tid & 63, w = tid >> 6;
    f32x16 acc[4];
    #pragma unroll
    for (int i = 0; i < 4; ++i)
        #pragma unroll
        for (int j = 0; j < 16; ++j) acc[i][j] = 0.0f;

    for (int kt = 0; kt < 16; ++kt) {
        const int k0 = kt * 64;
        #pragma unroll
        for (int i = 0; i < 4; ++i) {
            int widx = w*4 + i;
            int n = widx*64 + lane;
            int mt = n >> 8, kc = (n >> 5) & 7, r5 = n & 31;
            gload16(xb  + (size_t)(n0  + mt*32 + r5)*1024 + k0 + kc*8, lds + widx*1024);
            gload16(wxt + (size_t)(gc0 + mt*32 + r5)*1024 + k0 + kc*8, lds + 16384 + widx*1024);
        }
        __syncthreads();
        bf16x8 a[4];
        #pragma unroll
        for (int ks = 0; ks < 4; ++ks)
            a[ks] = *(const bf16x8*)(lds + w*4096 + (ks*2 + (lane>>5))*512 + (lane&31)*16);
        #pragma unroll
        for (int nt = 0; nt < 4; ++nt) {
            #pragma unroll
            for (int ks = 0; ks < 4; ++ks) {
                bf16x8 b = *(const bf16x8*)(lds + 16384 + nt*4096 + (ks*2 + (lane>>5))*512 + (lane&31)*16);
                acc[nt] = __builtin_amdgcn_mfma_f32_32x32x16_bf16(a[ks], b, acc[nt], 0, 0, 0);
            }
        }
        __syncthreads();
    }
    const int b_idx = n0 >> 8;
    const int t_base = n0 & 255;
    #pragma unroll
    for (int nt = 0; nt < 4; ++nt) {
        int gc = gc0 + nt*32 + (lane & 31);
        int gate = gc >> 10, col = gc & 1023;
        const float* bp = gate == 0 ? b0 : gate == 1 ? b1 : gate == 2 ? b2 : b3;
        float bias = bp[col];
        #pragma unroll
        for (int r = 0; r < 16; ++r) {
            int row = (r & 3) + 8*(r >> 2) + 4*(lane >> 5);
            int t = t_base + w*32 + row;
            p2[((size_t)t*32 + b_idx)*4096 + gc] = f2bf(acc[nt][r] + bias);
        }
    }
}

// ---------------- persistent BiLSTM recurrence ----------------
#define WPK   0          // 64 KB weight pack (B-frag order, 16x16x32)
#define REDF  65536      // 4 KB K-split partials F (also weight-pack scratch)
#define REDB  69632      // 4 KB partials B
#define CSTO  73728      // 1 KB c-state
#define STH_H 74752      // 512 B h bf16 stash [2 dir][16 row][8 col]
#define STH_O 75264      // 1 KB out fp32 stash [2 dir][16 row][8 col]
#define LDS_TOT 76288

extern __shared__ char smem[];

__global__ __launch_bounds__(256, 1) void k_lstm(
    const float* __restrict__ Wf, const float* __restrict__ Wi,
    const float* __restrict__ Wc, const float* __restrict__ Wo,
    const unsigned short* __restrict__ p2,
    unsigned short* __restrict__ hring,  // [256 slot][2 dir][32][1024] bf16
    unsigned* __restrict__ fl,           // flags u32 @ 64B stride: [half][128]
    float* __restrict__ out)             // [32][256][2048] fp32
{
    const int wg = blockIdx.x;
    const int bh = wg & 1;               // batch half (own dependency group)
    const int hc0 = (wg >> 1) * 8;       // owned h-cols
    const int tid = threadIdx.x;
    const int lane = tid & 63, w = tid >> 6;
    __shared__ int s_abort;
    if (tid == 0) s_abort = 0;

    // ---- pack recurrent weights (h-part rows 0..1023) into LDS frag order ----
    {
        unsigned short* scr = (unsigned short*)(smem + REDF);  // 4 KB scratch
        const float* Wp[4] = {Wf, Wi, Wc, Wo};
        for (int blk = 0; blk < 16; ++blk) {
            int r0 = blk * 64;
            {
                int g = tid >> 6, r = tid & 63;
                const float* src = Wp[g] + (size_t)(r0 + r) * 1024 + hc0;
                float4 v0 = *(const float4*)src;
                float4 v1 = *(const float4*)(src + 4);
                unsigned short* d = scr + r*32 + g*8;
                d[0]=f2bf(v0.x); d[1]=f2bf(v0.y); d[2]=f2bf(v0.z); d[3]=f2bf(v0.w);
                d[4]=f2bf(v1.x); d[5]=f2bf(v1.y); d[6]=f2bf(v1.z); d[7]=f2bf(v1.w);
            }
            __syncthreads();
            {
                int ksl = tid >> 7, nt = (tid >> 6) & 1, l = tid & 63;
                int gcl = nt*16 + (l & 15);
                int gp = gcl >> 3, hc = gcl & 7;
                int ks = (r0 >> 5) + ksl;
                unsigned short tmp[8];
                #pragma unroll
                for (int j = 0; j < 8; ++j) {
                    int kloc = ksl*32 + (l >> 4)*8 + j;
                    tmp[j] = scr[kloc*32 + gp*8 + hc];
                }
                char* dst = smem + WPK + (size_t)((nt*32 + ks)*64 + l)*16;
                ushort4 lo, hi;
                lo.x=tmp[0]; lo.y=tmp[1]; lo.z=tmp[2]; lo.w=tmp[3];
                hi.x=tmp[4]; hi.y=tmp[5]; hi.z=tmp[6]; hi.w=tmp[7];
                *(ushort4*)dst = lo; *((ushort4*)dst + 1) = hi;
            }
            __syncthreads();
        }
    }

    // ---- init c=0 (LDS), h(0)=0 into ring slot 0, publish tag 1 ----
    for (int i = tid; i < 256; i += 256) ((float*)(smem + CSTO))[i] = 0.0f;
    const int d2 = tid >> 7, t2 = tid & 127;
    const int eb = t2 >> 3, ehc = t2 & 7;
    const int ebg = bh*16 + eb, ehcg = hc0 + ehc;
    if ((tid & 1) == 0) {
        unsigned* dst = (unsigned*)(hring + (size_t)d2*32768 + (size_t)ebg*1024 + ehcg);
        __hip_atomic_store(dst, 0u, __ATOMIC_RELAXED, __HIP_MEMORY_SCOPE_AGENT);
    }
    __syncthreads();                              // drains init stores (vmcnt0)
    if (tid == 0)
        __hip_atomic_store(fl + (size_t)bh*2048 + (wg >> 1)*16, 1u,
                           __ATOMIC_RELAXED, __HIP_MEMORY_SCOPE_AGENT);

    for (int s = 0; s < 256; ++s) {
        const int tx = d2 ? (255 - s) : s;
        // P prefetch (cached; no h dependency; hidden under spin+MFMA loads)
        const unsigned short* pp = p2 + ((size_t)tx*32 + ebg)*4096 + ehcg;
        unsigned short pf = pp[0], pi = pp[1024], pc = pp[2048], po = pp[3072];

        // ---- wait: own half's 128 flags >= s+1 (waves 0+1, one lane/flag) ----
        if (w < 2) {
            const unsigned* pw = fl + (size_t)bh*2048 + (w*64 + lane)*16;
            const unsigned tag = (unsigned)(s + 1);
            long guard = 0;
            for (;;) {
                unsigned v = __hip_atomic_load(pw, __ATOMIC_RELAXED, __HIP_MEMORY_SCOPE_AGENT);
                if (__all(v >= tag)) break;
                if (++guard >= (1L << 21)) { if (lane == 0) s_abort = 1; break; }
                __builtin_amdgcn_s_sleep(1);
            }
        }
        __syncthreads();
        if (s_abort) break;

        // ---- MFMA with DIRECT global->VGPR A-frags (no LDS hop, no barrier)
        //      K split across wave pairs: wave w does K slice kh*512..+512,
        //      output cols nt*16..+16. A-frag: lane holds row lane&15, 8 elems
        //      at k = ks*32 + (lane>>4)*8 (m89 16x16x32 layout).
        {
            const int nt = w & 1, kh = w >> 1;
            const unsigned short* hsF = hring + (size_t)s*65536;
            const unsigned short* hsB = hsF + 32768;
            const int row = lane & 15, kcl = lane >> 4;
            const size_t rbase = (size_t)(bh*16 + row)*1024;
            bf16x8 fF[16], fB[16];
            #pragma unroll
            for (int k8 = 0; k8 < 16; ++k8) {       // 32 x 16B cached loads
                int kc = (kh*16 + k8)*4 + kcl;
                fF[k8] = *(const bf16x8*)(hsF + rbase + kc*8);
                fB[k8] = *(const bf16x8*)(hsB + rbase + kc*8);
            }
            f32x4 aF = {0.f,0.f,0.f,0.f}, aB = {0.f,0.f,0.f,0.f};
            #pragma unroll
            for (int k8 = 0; k8 < 16; ++k8) {
                int ks = kh*16 + k8;
                bf16x8 bfr = *(const bf16x8*)(smem + WPK + (size_t)((nt*32 + ks)*64 + lane)*16);
                aF = __builtin_amdgcn_mfma_f32_16x16x32_bf16(fF[k8], bfr, aF, 0, 0, 0);
                aB = __builtin_amdgcn_mfma_f32_16x16x32_bf16(fB[k8], bfr, aB, 0, 0, 0);
            }
            float* rf = (float*)(smem + REDF) + w*256;
            float* rb = (float*)(smem + REDB) + w*256;
            #pragma unroll
            for (int r = 0; r < 4; ++r) {
                int rw = (lane >> 4)*4 + r;
                rf[rw*16 + (lane & 15)] = aF[r];
                rb[rw*16 + (lane & 15)] = aB[r];
            }
        }
        __syncthreads();

        // ---- elementwise: t<128 does F, t>=128 does B; stash h+out in LDS ----
        {
            const char* red = smem + (d2 ? REDB : REDF);
            float* cst = (float*)(smem + CSTO) + (size_t)(d2*16 + eb)*8 + ehc;
            unsigned short pv[4] = {pf, pi, pc, po};
            float pre[4];
            #pragma unroll
            for (int g = 0; g < 4; ++g) {
                int gc = g*8 + ehc;
                int nt = gc >> 4, col = gc & 15;
                float s0 = ((const float*)red)[nt*256 + eb*16 + col];
                float s1 = ((const float*)red)[(2 + nt)*256 + eb*16 + col];
                pre[g] = s0 + s1 + bf2f(pv[g]);
            }
            float fg = sigm(pre[0]), ig = sigm(pre[1]), gg = tanh_(pre[2]), og = sigm(pre[3]);
            float cn = fg * (*cst) + ig * gg;
            *cst = cn;
            float hv = og * tanh_(cn);
            ((unsigned short*)(smem + STH_H))[d2*128 + t2] = f2bf(hv);
            ((float*)(smem + STH_O))[d2*128 + t2] = hv;
        }
        __syncthreads();

        // ---- h publish into virgin ring slot s+1: 32 x 16B sc1 stores ----
        if (s < 255) {
            if (tid < 32) {
                int d2s = tid >> 4, ebs = tid & 15;
                u32x4 v = *(const u32x4*)(smem + STH_H + (d2s*16 + ebs)*16);
                gstore16_sc1(hring + (size_t)(s + 1)*65536 + (size_t)d2s*32768
                                   + (size_t)(bh*16 + ebs)*1024 + hc0, v);
            }
            __syncthreads();                      // drains h stores (vmcnt0)
            if (tid == 0)
                __hip_atomic_store(fl + (size_t)bh*2048 + (wg >> 1)*16, (unsigned)(s + 2),
                                   __ATOMIC_RELAXED, __HIP_MEMORY_SCOPE_AGENT);
        }

        // ---- out stores (post-publish, off critical path): 16B chunks ----
        if (tid >= 64 && tid < 128) {
            int i = tid - 64;
            int chunk = i >> 1, half = i & 1;       // chunk = d2s*16 + ebs
            int d2s = chunk >> 4, ebs = chunk & 15;
            int txs = d2s ? (255 - s) : s;
            float4 v = *(const float4*)(smem + STH_O + chunk*32 + half*16);
            *(float4*)(out + ((size_t)(bh*16 + ebs)*256 + txs)*2048
                           + (size_t)d2s*1024 + hc0 + half*4) = v;
        }
    }
}

extern "C" void kernel_launch(void* const* d_in, const int* in_sizes, int n_in,
                              void* d_out, int out_size, void* d_ws, size_t ws_size,
                              hipStream_t stream) {
    const float* x  = (const float*)d_in[0];
    const float* Wf = (const float*)d_in[1]; const float* bf_ = (const float*)d_in[2];
    const float* Wi = (const float*)d_in[3]; const float* bi_ = (const float*)d_in[4];
    const float* Wc = (const float*)d_in[5]; const float* bc_ = (const float*)d_in[6];
    const float* Wo = (const float*)d_in[7]; const float* bo_ = (const float*)d_in[8];
    char* ws = (char*)d_ws;
    unsigned short* xb    = (unsigned short*)(ws + XB_OFF);
    unsigned short* wxt   = (unsigned short*)(ws + WXT_OFF);
    unsigned short* p2    = (unsigned short*)(ws + P2_OFF);
    unsigned short* hring = (unsigned short*)(ws + XB_OFF);   // overlays dead xb/wxt
    unsigned*       fl    = (unsigned*)(ws + FLG_OFF);

    hipMemsetAsync(ws + FLG_OFF, 0, FLG_SZ, stream);
    k_cvt_x<<<8192, 256, 0, stream>>>(x, xb, 32*256*1024);
    k_pack_wxt<<<dim3(16, 64), 256, 0, stream>>>(Wf, Wi, Wc, Wo, wxt);
    k_pgemm<<<dim3(64, 32), 256, 0, stream>>>(xb, wxt, bf_, bi_, bc_, bo_, p2);
    hipFuncSetAttribute((const void*)k_lstm, hipFuncAttributeMaxDynamicSharedMemorySize, LDS_TOT);
    k_lstm<<<256, 256, LDS_TOT, stream>>>(Wf, Wi, Wc, Wo, p2, hring, fl, (float*)d_out);
}